// Round 7
// baseline (3195.727 us; speedup 1.0000x reference)
//
#include <hip/hip_runtime.h>
#include <stdint.h>

typedef unsigned short u16;
typedef unsigned int u32;
typedef unsigned long long u64;
typedef __attribute__((ext_vector_type(8))) short short8;   // 8 x bf16
typedef __attribute__((ext_vector_type(4))) float f32x4;
typedef __attribute__((ext_vector_type(4))) int int4v;

#define SEQ 256
#define NWG 65          // 64 gate (16 also compute d slices) + 1 y
#define A_ELE 49152     // elements per A ring slot (bf16): 6144 chunks x 8
#define D_ELE 16384

__device__ __forceinline__ u16 f2bf(float f) {
  u32 u = __float_as_uint(f);
  u += 0x7FFFu + ((u >> 16) & 1u);
  return (u16)(u >> 16);
}
__device__ __forceinline__ short8 cvt8(const float* __restrict__ p) {
  short8 r;
#pragma unroll
  for (int j = 0; j < 8; ++j) r[j] = (short)f2bf(p[j]);
  return r;
}
__device__ __forceinline__ short8 cvt8v(const float* __restrict__ p) {  // 2x float4
  f32x4 a = *(const f32x4*)p, b = *(const f32x4*)(p + 4);
  short8 r;
#pragma unroll
  for (int j = 0; j < 4; ++j) { r[j] = (short)f2bf(a[j]); r[4 + j] = (short)f2bf(b[j]); }
  return r;
}
__device__ __forceinline__ float fast_tanh(float x) {
  return 1.0f - 2.0f / (1.0f + __expf(2.0f * x));
}
__device__ __forceinline__ float fast_sig(float x) {
  return 1.0f / (1.0f + __expf(-x));
}

union V16 { short8 s; u64 q[2]; };
// device-coherent 16B load/store (agent scope) — R4-proven constructs only
__device__ __forceinline__ short8 ldc16(const u16* p) {
  V16 v;
  v.q[0] = __hip_atomic_load((const u64*)p,     __ATOMIC_RELAXED, __HIP_MEMORY_SCOPE_AGENT);
  v.q[1] = __hip_atomic_load((const u64*)p + 1, __ATOMIC_RELAXED, __HIP_MEMORY_SCOPE_AGENT);
  return v.s;
}
__device__ __forceinline__ void stc16(u16* p, const u64* s) {
  __hip_atomic_store((u64*)p,     s[0], __ATOMIC_RELAXED, __HIP_MEMORY_SCOPE_AGENT);
  __hip_atomic_store((u64*)p + 1, s[1], __ATOMIC_RELAXED, __HIP_MEMORY_SCOPE_AGENT);
}
__device__ __forceinline__ void pollge(u32* p, u32 v) {
  while (__hip_atomic_load(p, __ATOMIC_RELAXED, __HIP_MEMORY_SCOPE_AGENT) < v) {}
}
__device__ __forceinline__ void setflag(u32* p, u32 v) {
  __hip_atomic_store(p, v, __ATOMIC_RELAXED, __HIP_MEMORY_SCOPE_AGENT);
}
#define VMCNT0() asm volatile("s_waitcnt vmcnt(0)" ::: "memory")

// ---------------------------------------------------------------------------
// Prep: feat_0 -> A slot0 feat section; zero slot0 h section; zero flags.
// A-frag chunk layout: chunk=(kb*4+mt)*64+lane; lane holds
// A[m=mt*16+(lane&15)][k=kb*32+(lane>>4)*8+j], j=0..7.
// ---------------------------------------------------------------------------
__global__ void prep_kernel(const float* __restrict__ x, const float* __restrict__ W_fx,
                            const float* __restrict__ b_fx,
                            u16* __restrict__ Abuf0, u32* __restrict__ flags) {
  int b = blockIdx.x, tid = threadIdx.x;
  if (b < 64) {
    int gidx = b * 256 + tid;          // 16384 elements of feat_0 [64][256]
    int chunk = gidx >> 3, j = gidx & 7;
    int kb = chunk >> 8, mt = (chunk >> 6) & 3, l = chunk & 63;
    int m = mt * 16 + (l & 15);
    int c = kb * 32 + (l >> 4) * 8 + j;
    float s = b_fx[c];
    const float* xr = x + m * 64;      // t = 0
    const float* wr = W_fx + c * 64;
    for (int k = 0; k < 64; ++k) s += xr[k] * wr[k];
    Abuf0[chunk * 8 + j] = f2bf(fast_tanh(s));
  } else {
    for (int it = 0; it < 16; ++it) {  // zero h-section of slot0: chunks 2048..6143
      int chunk = it * 256 + tid;
      *(int4v*)(Abuf0 + (2048 + chunk) * 8) = (int4v){0, 0, 0, 0};
    }
    for (int k = 0; k < 6; ++k) {
      int i = k * 256 + tid;
      if (i < 1536) flags[i] = 0u;
    }
  }
}

// ---------------------------------------------------------------------------
// Persistent recurrent kernel. 65 WGs x 256 threads.
// flags: hflag[64] @0 (stride 16), dflag[16] @1024 (stride 16), fc @1344.
//   hflag[wg]=t+1 after gate wg stored h_{t+1} ; consumers poll >= t for h_t
//   dflag[dw]=t+1 after d-gate dw stored d_t   ; y polls >= t+1
//   fc      =t+1 after y stored feat_{t+1}     ; gates poll >= t for feat_t
// Chain per step: gates(h,d) -> y(y,feat) -> gates : 2 cross-WG hops.
// ---------------------------------------------------------------------------
__global__ void __launch_bounds__(256, 1)
rnn_kernel(const float* __restrict__ x, const float* __restrict__ msel,
           const float* __restrict__ W_fx, const float* __restrict__ b_fx,
           const float* __restrict__ W_ih, const float* __restrict__ W_hh,
           const float* __restrict__ b_ih, const float* __restrict__ b_hh,
           const float* __restrict__ W_hx, const float* __restrict__ b_hx,
           const float* __restrict__ W_out, const float* __restrict__ b_out,
           float* __restrict__ out,
           u16* __restrict__ Abase, u16* __restrict__ dbase,
           u32* __restrict__ flags) {
  __shared__ __attribute__((aligned(16))) char smem[109568];
  const int wgid = blockIdx.x;
  const int tid = threadIdx.x;
  const int wv = tid >> 6, ln = tid & 63;
  u32* hflag = flags;           // 64 x stride16
  u32* dflag = flags + 1024;    // 16 x stride16
  u32* fcv   = flags + 1344;

  if (wgid < 64) {
    // ===== gate WG: 8 hidden units; wg<16 also computes 16 cols of d =====
    const int wg = wgid;
    const bool isD = (wg < 16);
    float* red = (float*)smem;                 // [4 wv][12 tile][64][4] f32 = 49152
    u16* hstage = (u16*)(smem + 49152);        // 1024 B
    u16* dstage = (u16*)(smem + 50176);        // 2048 B
    const int c15 = ln & 15, q = ln >> 4;
    short8 Breg[6][2];
#pragma unroll
    for (int kk = 0; kk < 6; ++kk) {
      int kb = wv * 6 + kk;
#pragma unroll
      for (int nt = 0; nt < 2; ++nt) {
        int gate = nt * 2 + (c15 >> 3), unit = c15 & 7;
        int row = gate * 512 + wg * 8 + unit;
        int k = kb * 32 + q * 8;
        const float* src = (k < 256) ? (W_ih + row * 256 + k) : (W_hh + row * 512 + (k - 256));
        Breg[kk][nt] = cvt8(src);
      }
    }
    float bsum_r[2][4];
#pragma unroll
    for (int it = 0; it < 2; ++it) {
      int u = (it * 256 + tid) & 7;
#pragma unroll
      for (int g = 0; g < 4; ++g) {
        int row = g * 512 + wg * 8 + u;
        bsum_r[it][g] = b_ih[row] + b_hh[row];
      }
    }
    short8 Bd[6];
    float bd8[8];
    if (isD) {
      int colB = wg * 16 + c15;                // this WG's d col for B frags
#pragma unroll
      for (int kk = 0; kk < 6; ++kk) {
        int kb = wv * 6 + kk;
        if (kb >= 8) Bd[kk] = cvt8(W_hx + colB * 512 + (kb - 8) * 32 + q * 8);
      }
      if (tid < 128) {
        int jh = tid & 1;
#pragma unroll
        for (int j = 0; j < 8; ++j) bd8[j] = b_hx[wg * 16 + jh * 8 + j];
      }
    }
    float creg[2] = {0.f, 0.f};                // c-state in registers
    const int kbW = 8 + (wg >> 2), qW = wg & 3;
    int r = 0, rn = 1;
    for (int t = 0; t < SEQ; ++t) {
      if (tid < 64) pollge(&hflag[tid * 16], (u32)t);
      else if (tid == 64) pollge(fcv, (u32)t);
      __syncthreads();
      const u16* A = Abase + r * A_ELE;
      u16* An = Abase + rn * A_ELE;
      u16* dbufR = dbase + (t & 1) * D_ELE;
      f32x4 acc[2][4];
#pragma unroll
      for (int nt = 0; nt < 2; nt++)
#pragma unroll
        for (int mt = 0; mt < 4; mt++) acc[nt][mt] = (f32x4){0.f, 0.f, 0.f, 0.f};
      f32x4 dacc[4];
#pragma unroll
      for (int mt = 0; mt < 4; ++mt) dacc[mt] = (f32x4){0.f, 0.f, 0.f, 0.f};
#pragma unroll
      for (int kk = 0; kk < 6; ++kk) {         // wave K-split: kb in [6wv, 6wv+6)
        int kb = wv * 6 + kk;
        short8 a[4];
#pragma unroll
        for (int mt = 0; mt < 4; mt++)
          a[mt] = ldc16(A + ((kb * 4 + mt) * 64 + ln) * 8);
#pragma unroll
        for (int nt = 0; nt < 2; nt++)
#pragma unroll
          for (int mt = 0; mt < 4; mt++)
            acc[nt][mt] = __builtin_amdgcn_mfma_f32_16x16x32_bf16(a[mt], Breg[kk][nt], acc[nt][mt], 0, 0, 0);
        if (isD && kb >= 8)
#pragma unroll
          for (int mt = 0; mt < 4; mt++)
            dacc[mt] = __builtin_amdgcn_mfma_f32_16x16x32_bf16(a[mt], Bd[kk], dacc[mt], 0, 0, 0);
      }
      // one-shot 4-wave reduction staging (12 tiles/wave)
#pragma unroll
      for (int nt = 0; nt < 2; nt++)
#pragma unroll
        for (int mt = 0; mt < 4; mt++)
          *(f32x4*)(red + ((wv * 12 + nt * 4 + mt) * 64 + ln) * 4) = acc[nt][mt];
      if (isD)
#pragma unroll
        for (int mt = 0; mt < 4; mt++)
          *(f32x4*)(red + ((wv * 12 + 8 + mt) * 64 + ln) * 4) = dacc[mt];
      __syncthreads();
      // LSTM cell: 512 (m,u) items, 2/thread; sum 4 wave partials inline
#pragma unroll
      for (int it = 0; it < 2; ++it) {
        int item = it * 256 + tid;
        int m = item >> 3, u = item & 7;
        int mt = m >> 4, lq = ((m & 15) >> 2) * 16, reg = m & 3;
        float g4[4];
#pragma unroll
        for (int g = 0; g < 4; ++g) {
          float s = bsum_r[it][g];
          int base = ((g >> 1) * 4 + mt) * 64 + lq + (g & 1) * 8 + u;
#pragma unroll
          for (int w = 0; w < 4; ++w) s += red[(w * 12 * 64 + base) * 4 + reg];
          g4[g] = s;
        }
        float ii = fast_sig(g4[0]), ff = fast_sig(g4[1]);
        float gg = fast_tanh(g4[2]), oo = fast_sig(g4[3]);
        float cn = ff * creg[it] + ii * gg;
        creg[it] = cn;
        float h = oo * fast_tanh(cn);
        hstage[(mt * 16 + (m & 15)) * 8 + u] = f2bf(h);
      }
      // d finalize: 1024 outputs, tid<128 handle (m=tid>>1, cols jh*8..+8)
      if (isD && tid < 128) {
        int m = tid >> 1, jh = tid & 1;
        int mt = m >> 4, qm = (m & 15) >> 2, reg = m & 3;
#pragma unroll
        for (int j = 0; j < 8; ++j) {
          int c = jh * 8 + j;
          float s = bd8[j];
          int base = (8 + mt) * 64 + qm * 16 + c;
#pragma unroll
          for (int w = 0; w < 4; ++w) s += red[(w * 12 * 64 + base) * 4 + reg];
          dstage[tid * 8 + j] = f2bf(fast_tanh(s));
        }
      }
      __syncthreads();
      if (tid < 64) {   // h store: this WG's kb region (1KB)
        int mt2 = tid >> 4, m15 = tid & 15;
        stc16(An + (((kbW * 4 + mt2) * 64 + qW * 16 + m15) * 8),
              (const u64*)(hstage + tid * 8));
      }
      if (isD && tid < 128) {   // d store: this WG's 16-col slice (2KB)
        int m = tid >> 1, jh = tid & 1;
        int mt = m >> 4, qk = (wg & 1) * 2 + jh;
        stc16(dbufR + (((wg >> 1) * 4 + mt) * 64 + qk * 16 + (m & 15)) * 8,
              (const u64*)(dstage + tid * 8));
      }
      VMCNT0();
      __syncthreads();
      if (tid == 0) setflag(&hflag[wg * 16], (u32)(t + 1));
      else if (tid == 1 && isD) setflag(&dflag[wg * 16], (u32)(t + 1));
      r = rn; rn = (rn == 2) ? 0 : rn + 1;
    }
  } else {
    // ===== y WG: y = d@Wout^T + b; feat_{t+1} = mix*fe(y)+(1-mix)*fe(x) =====
    float* red = (float*)smem;                 // [4 wv][16 tile][64][4] = 64KB
    u16* ystage = (u16*)(smem + 65536);        // [64][80] = 10240B
    u16* fstage = (u16*)(smem + 75776);        // [64][264] = 33792B
    const int c15 = ln & 15, qq = ln >> 4;
    short8 WoR[2][4], WfR[2][4];
#pragma unroll
    for (int kk = 0; kk < 2; ++kk) {
      int koffo = (wv * 2 + kk) * 32 + qq * 8;   // W_out K-offset (K=256)
      int kofff = kk * 32 + qq * 8;              // W_fx K-offset (K=64)
#pragma unroll
      for (int nt = 0; nt < 4; ++nt) {
        WoR[kk][nt] = cvt8(W_out + (nt * 16 + c15) * 256 + koffo);
        WfR[kk][nt] = cvt8(W_fx + ((wv * 4 + nt) * 16 + c15) * 64 + kofff);
      }
    }
    float bout_r = b_out[wv * 16 + c15];
    float bfx_r[4];
#pragma unroll
    for (int nt = 0; nt < 4; ++nt) bfx_r[nt] = b_fx[(wv * 4 + nt) * 16 + c15];

    int rn = 1;
    for (int t = 0; t < SEQ; ++t) {
      // precompute tf = (1-mix)*tanh(x[t+1]@Wfx^T + b) off the critical path
      f32x4 tfr[4][4];
      float mix = 0.f;
      if (t < SEQ - 1) {
        mix = msel[t + 1];
        f32x4 tf[4][4];
#pragma unroll
        for (int nt = 0; nt < 4; nt++)
#pragma unroll
          for (int mt = 0; mt < 4; mt++) tf[nt][mt] = (f32x4){0.f, 0.f, 0.f, 0.f};
#pragma unroll
        for (int kb = 0; kb < 2; ++kb) {
          short8 xa[4];
#pragma unroll
          for (int mt = 0; mt < 4; ++mt)
            xa[mt] = cvt8v(x + ((t + 1) * 64 + mt * 16 + c15) * 64 + kb * 32 + qq * 8);
#pragma unroll
          for (int nt = 0; nt < 4; nt++)
#pragma unroll
            for (int mt = 0; mt < 4; mt++)
              tf[nt][mt] = __builtin_amdgcn_mfma_f32_16x16x32_bf16(xa[mt], WfR[kb][nt], tf[nt][mt], 0, 0, 0);
        }
        float om = 1.f - mix;
#pragma unroll
        for (int nt = 0; nt < 4; nt++)
#pragma unroll
          for (int mt = 0; mt < 4; mt++)
#pragma unroll
            for (int r2 = 0; r2 < 4; r2++)
              tfr[nt][mt][r2] = om * fast_tanh(tf[nt][mt][r2] + bfx_r[nt]);
      }
      if (tid < 16) pollge(&dflag[tid * 16], (u32)(t + 1));
      __syncthreads();
      const u16* dbufR = dbase + (t & 1) * D_ELE;
      u16* An = Abase + rn * A_ELE;
      short8 da[2][4];
#pragma unroll
      for (int kk = 0; kk < 2; ++kk)
#pragma unroll
        for (int mt = 0; mt < 4; ++mt)
          da[kk][mt] = ldc16(dbufR + (((wv * 2 + kk) * 4 + mt) * 64 + ln) * 8);
      f32x4 acc[4][4];
#pragma unroll
      for (int nt = 0; nt < 4; nt++)
#pragma unroll
        for (int mt = 0; mt < 4; mt++) acc[nt][mt] = (f32x4){0.f, 0.f, 0.f, 0.f};
#pragma unroll
      for (int kk = 0; kk < 2; ++kk)
#pragma unroll
        for (int nt = 0; nt < 4; nt++)
#pragma unroll
          for (int mt = 0; mt < 4; mt++)
            acc[nt][mt] = __builtin_amdgcn_mfma_f32_16x16x32_bf16(da[kk][mt], WoR[kk][nt], acc[nt][mt], 0, 0, 0);
#pragma unroll
      for (int nt = 0; nt < 4; nt++)
#pragma unroll
        for (int mt = 0; mt < 4; mt++)
          *(f32x4*)(red + ((wv * 16 + nt * 4 + mt) * 64 + ln) * 4) = acc[nt][mt];
      __syncthreads();
      // wave wv finalizes output cols [wv*16, wv*16+16)
#pragma unroll
      for (int mt = 0; mt < 4; ++mt) {
        f32x4 s = (f32x4){0.f, 0.f, 0.f, 0.f};
#pragma unroll
        for (int w2 = 0; w2 < 4; ++w2)
          s += *(const f32x4*)(red + ((w2 * 16 + wv * 4 + mt) * 64 + ln) * 4);
#pragma unroll
        for (int r2 = 0; r2 < 4; ++r2) {
          float yv = s[r2] + bout_r;
          int row = mt * 16 + qq * 4 + r2;
          out[t * 4096 + row * 64 + wv * 16 + c15] = yv;   // f32 output
          ystage[row * 80 + wv * 16 + c15] = f2bf(yv);
        }
      }
      __syncthreads();
      if (t < SEQ - 1) {
        f32x4 au[4][4];
#pragma unroll
        for (int nt = 0; nt < 4; nt++)
#pragma unroll
          for (int mt = 0; mt < 4; mt++) au[nt][mt] = (f32x4){0.f, 0.f, 0.f, 0.f};
#pragma unroll
        for (int kb = 0; kb < 2; ++kb) {
          int koff = kb * 32 + qq * 8;
          short8 ya[4];
#pragma unroll
          for (int mt = 0; mt < 4; mt++)
            ya[mt] = *(const short8*)(ystage + (mt * 16 + c15) * 80 + koff);
#pragma unroll
          for (int nt = 0; nt < 4; nt++)
#pragma unroll
            for (int mt = 0; mt < 4; mt++)
              au[nt][mt] = __builtin_amdgcn_mfma_f32_16x16x32_bf16(ya[mt], WfR[kb][nt], au[nt][mt], 0, 0, 0);
        }
#pragma unroll
        for (int nt = 0; nt < 4; nt++)
#pragma unroll
          for (int mt = 0; mt < 4; mt++)
#pragma unroll
            for (int r2 = 0; r2 < 4; r2++) {
              float fv = mix * fast_tanh(au[nt][mt][r2] + bfx_r[nt]) + tfr[nt][mt][r2];
              int row = mt * 16 + qq * 4 + r2;
              fstage[row * 264 + (wv * 4 + nt) * 16 + c15] = f2bf(fv);
            }
        __syncthreads();
#pragma unroll
        for (int it = 0; it < 8; ++it) {       // fstage -> An feat section
          int ch = it * 256 + tid;
          int kb = ch >> 8, l = ch & 63;
          int m = ((ch >> 6) & 3) * 16 + (l & 15);
          int k = kb * 32 + (l >> 4) * 8;
          V16 v; v.s = *(const short8*)(fstage + m * 264 + k);
          stc16(An + ch * 8, v.q);
        }
        VMCNT0();
        __syncthreads();
        if (tid == 0) setflag(fcv, (u32)(t + 1));
      }
      rn = (rn == 2) ? 0 : rn + 1;
    }
  }
}

extern "C" void kernel_launch(void* const* d_in, const int* in_sizes, int n_in,
                              void* d_out, int out_size, void* d_ws, size_t ws_size,
                              hipStream_t stream) {
  const float* x     = (const float*)d_in[0];
  const float* msel  = (const float*)d_in[1];
  const float* W_fx  = (const float*)d_in[2];
  const float* b_fx  = (const float*)d_in[3];
  const float* W_ih  = (const float*)d_in[4];
  const float* W_hh  = (const float*)d_in[5];
  const float* b_ih  = (const float*)d_in[6];
  const float* b_hh  = (const float*)d_in[7];
  const float* W_hx  = (const float*)d_in[8];
  const float* b_hx  = (const float*)d_in[9];
  const float* W_out = (const float*)d_in[10];
  const float* b_out = (const float*)d_in[11];

  uint8_t* ws = (uint8_t*)d_ws;
  u16* Abase = (u16*)ws;                    // ring of 3 x 98304 B
  u16* dbase = (u16*)(ws + 294912);         // ring of 2 x 32768 B
  u32* flags = (u32*)(ws + 360448);         // 6144 B

  prep_kernel<<<65, 256, 0, stream>>>(x, W_fx, b_fx, Abase, flags);
  rnn_kernel<<<NWG, 256, 0, stream>>>(x, msel, W_fx, b_fx, W_ih, W_hh, b_ih, b_hh,
                                      W_hx, b_hx, W_out, b_out,
                                      (float*)d_out, Abase, dbase, flags);
}